// Round 1
// baseline (677.763 us; speedup 1.0000x reference)
//
#include <hip/hip_runtime.h>
#include <math.h>

#define BB 32
#define SS 4096
#define HH 1024
#define CHUNKS 16                      // blocks per batch
#define ROWS_PER_BLOCK (SS / CHUNKS)   // 256
#define WAVES 4
#define ROWS_PER_WAVE (ROWS_PER_BLOCK / WAVES)  // 64
#define UNROLL 4

// Pass 1: fused energy + (un-normalized) softmax-weighted accumulation.
// tanh bounds energy to [-1,1] so exp(e) is safe without max subtraction.
__global__ __launch_bounds__(256, 2) void attn_pass1(
    const float* __restrict__ x, const float* __restrict__ w,
    float* __restrict__ pc, float* __restrict__ pl)
{
    const int tid  = threadIdx.x;
    const int wave = tid >> 6;
    const int lane = tid & 63;
    const int blk  = blockIdx.x;            // b*CHUNKS + chunk
    const int b    = blk / CHUNKS;
    const int chunk= blk % CHUNKS;

    const float* xb = x + (long long)b * SS * HH
                        + (long long)chunk * ROWS_PER_BLOCK * HH
                        + (long long)wave * ROWS_PER_WAVE * HH;

    // w fragment: lane handles h = k*256 + lane*4 .. +3
    float4 wv[4];
#pragma unroll
    for (int k = 0; k < 4; ++k)
        wv[k] = *(const float4*)(w + k * 256 + lane * 4);

    float4 acc[4];
#pragma unroll
    for (int k = 0; k < 4; ++k) acc[k] = make_float4(0.f, 0.f, 0.f, 0.f);
    float l = 0.f;

    for (int r = 0; r < ROWS_PER_WAVE; r += UNROLL) {
        float4 xv[UNROLL][4];
        const float* p = xb + (long long)r * HH + lane * 4;
#pragma unroll
        for (int u = 0; u < UNROLL; ++u)
#pragma unroll
            for (int k = 0; k < 4; ++k)
                xv[u][k] = *(const float4*)(p + u * HH + k * 256);

        float s[UNROLL];
#pragma unroll
        for (int u = 0; u < UNROLL; ++u) {
            float t = 0.f;
#pragma unroll
            for (int k = 0; k < 4; ++k) {
                t = fmaf(xv[u][k].x, wv[k].x, t);
                t = fmaf(xv[u][k].y, wv[k].y, t);
                t = fmaf(xv[u][k].z, wv[k].z, t);
                t = fmaf(xv[u][k].w, wv[k].w, t);
            }
            s[u] = t;
        }
        // 64-lane butterfly reduce, 4 independent chains interleaved
#pragma unroll
        for (int off = 32; off >= 1; off >>= 1)
#pragma unroll
            for (int u = 0; u < UNROLL; ++u)
                s[u] += __shfl_xor(s[u], off, 64);

#pragma unroll
        for (int u = 0; u < UNROLL; ++u) {
            float pw = __expf(tanhf(s[u]));   // e in [-1,1] -> no max needed
            l += pw;
#pragma unroll
            for (int k = 0; k < 4; ++k) {
                acc[k].x = fmaf(pw, xv[u][k].x, acc[k].x);
                acc[k].y = fmaf(pw, xv[u][k].y, acc[k].y);
                acc[k].z = fmaf(pw, xv[u][k].z, acc[k].z);
                acc[k].w = fmaf(pw, xv[u][k].w, acc[k].w);
            }
        }
    }

    // Block-level reduce across the 4 waves via LDS, write one partial/block.
    __shared__ float lds_c[WAVES * HH];   // 16 KB
    __shared__ float lds_l[WAVES];
#pragma unroll
    for (int k = 0; k < 4; ++k)
        *(float4*)(lds_c + wave * HH + k * 256 + lane * 4) = acc[k];
    if (lane == 0) lds_l[wave] = l;   // l is lane-replicated within a wave
    __syncthreads();

    float4 c = *(const float4*)(lds_c + tid * 4);
#pragma unroll
    for (int wv2 = 1; wv2 < WAVES; ++wv2) {
        float4 o = *(const float4*)(lds_c + wv2 * HH + tid * 4);
        c.x += o.x; c.y += o.y; c.z += o.z; c.w += o.w;
    }
    *(float4*)(pc + (long long)blk * HH + tid * 4) = c;
    if (tid == 0)
        pl[blk] = lds_l[0] + lds_l[1] + lds_l[2] + lds_l[3];
}

// Pass 2: combine CHUNKS partials per batch, normalize.
__global__ __launch_bounds__(256) void attn_pass2(
    const float* __restrict__ pc, const float* __restrict__ pl,
    float* __restrict__ out)
{
    const int b = blockIdx.x;
    const int t = threadIdx.x;
    float l = 0.f;
    float4 c = make_float4(0.f, 0.f, 0.f, 0.f);
#pragma unroll
    for (int i = 0; i < CHUNKS; ++i) {
        const int blk = b * CHUNKS + i;
        l += pl[blk];
        float4 o = *(const float4*)(pc + (long long)blk * HH + t * 4);
        c.x += o.x; c.y += o.y; c.z += o.z; c.w += o.w;
    }
    const float inv = 1.f / l;
    float4 r = make_float4(c.x * inv, c.y * inv, c.z * inv, c.w * inv);
    *(float4*)(out + (long long)b * HH + t * 4) = r;
}

extern "C" void kernel_launch(void* const* d_in, const int* in_sizes, int n_in,
                              void* d_out, int out_size, void* d_ws, size_t ws_size,
                              hipStream_t stream) {
    const float* x = (const float*)d_in[0];   // [B,S,H] fp32
    const float* w = (const float*)d_in[1];   // [H] fp32
    float* out = (float*)d_out;               // [B,H] fp32

    float* pc = (float*)d_ws;                           // [B*CHUNKS, H]
    float* pl = pc + (size_t)BB * CHUNKS * HH;          // [B*CHUNKS]

    attn_pass1<<<BB * CHUNKS, 256, 0, stream>>>(x, w, pc, pl);
    attn_pass2<<<BB, 256, 0, stream>>>(pc, pl, out);
}

// Round 2
// 676.405 us; speedup vs baseline: 1.0020x; 1.0020x over previous
//
#include <hip/hip_runtime.h>
#include <math.h>

#define BB 32
#define SS 4096
#define HH 1024
#define CHUNKS 32                      // blocks per batch
#define ROWS_PER_BLOCK (SS / CHUNKS)   // 128
#define WAVES 4
#define ROWS_PER_WAVE (ROWS_PER_BLOCK / WAVES)  // 32
#define UNROLL 2                       // rows per process group

// pw = exp(tanh(s)); tanh via exp+rcp (no branches, no precise div).
// tanh bounds energy to [-1,1] so no softmax max-subtraction is needed.
__device__ __forceinline__ float softmax_w(float s) {
    float t  = __expf(2.0f * s);                          // v_exp_f32
    float th = 1.0f - 2.0f * __builtin_amdgcn_rcpf(t + 1.0f); // v_rcp_f32
    return __expf(th);
}

__device__ __forceinline__ void load_rows(float4 (&buf)[UNROLL][4],
                                          const float* __restrict__ p) {
#pragma unroll
    for (int u = 0; u < UNROLL; ++u)
#pragma unroll
        for (int k = 0; k < 4; ++k)
            buf[u][k] = *(const float4*)(p + u * HH + k * 256);
}

__device__ __forceinline__ void process_rows(const float4 (&buf)[UNROLL][4],
                                             const float4 (&wv)[4],
                                             float4 (&acc)[4], float& l) {
    float s[UNROLL];
#pragma unroll
    for (int u = 0; u < UNROLL; ++u) {
        float t = 0.f;
#pragma unroll
        for (int k = 0; k < 4; ++k) {
            t = fmaf(buf[u][k].x, wv[k].x, t);
            t = fmaf(buf[u][k].y, wv[k].y, t);
            t = fmaf(buf[u][k].z, wv[k].z, t);
            t = fmaf(buf[u][k].w, wv[k].w, t);
        }
        s[u] = t;
    }
    // 64-lane butterfly reduce, UNROLL independent chains interleaved
#pragma unroll
    for (int off = 32; off >= 1; off >>= 1)
#pragma unroll
        for (int u = 0; u < UNROLL; ++u)
            s[u] += __shfl_xor(s[u], off, 64);

#pragma unroll
    for (int u = 0; u < UNROLL; ++u) {
        float pw = softmax_w(s[u]);
        l += pw;
#pragma unroll
        for (int k = 0; k < 4; ++k) {
            acc[k].x = fmaf(pw, buf[u][k].x, acc[k].x);
            acc[k].y = fmaf(pw, buf[u][k].y, acc[k].y);
            acc[k].z = fmaf(pw, buf[u][k].z, acc[k].z);
            acc[k].w = fmaf(pw, buf[u][k].w, acc[k].w);
        }
    }
}

// Fused energy + un-normalized softmax-weighted accumulation, one x pass.
// Software-pipelined: double-buffered register tiles keep loads in flight
// across the dot->reduce->tanh->acc dependency chain.
__global__ __launch_bounds__(256, 3) void attn_pass1(
    const float* __restrict__ x, const float* __restrict__ w,
    float* __restrict__ pc, float* __restrict__ pl)
{
    const int tid  = threadIdx.x;
    const int wave = tid >> 6;
    const int lane = tid & 63;
    const int blk  = blockIdx.x;            // b*CHUNKS + chunk
    const int b    = blk / CHUNKS;
    const int chunk= blk % CHUNKS;

    const float* xb = x + (long long)b * SS * HH
                        + (long long)chunk * ROWS_PER_BLOCK * HH
                        + (long long)wave * ROWS_PER_WAVE * HH
                        + lane * 4;

    float4 wv[4];
#pragma unroll
    for (int k = 0; k < 4; ++k)
        wv[k] = *(const float4*)(w + k * 256 + lane * 4);

    float4 acc[4];
#pragma unroll
    for (int k = 0; k < 4; ++k) acc[k] = make_float4(0.f, 0.f, 0.f, 0.f);
    float l = 0.f;

    float4 bufA[UNROLL][4], bufB[UNROLL][4];
    load_rows(bufA, xb);                              // prologue: rows 0..U-1

    for (int r = 0; r < ROWS_PER_WAVE; r += 2 * UNROLL) {
        load_rows(bufB, xb + (long long)(r + UNROLL) * HH);      // prefetch
        process_rows(bufA, wv, acc, l);
        if (r + 2 * UNROLL < ROWS_PER_WAVE)
            load_rows(bufA, xb + (long long)(r + 2 * UNROLL) * HH); // prefetch
        process_rows(bufB, wv, acc, l);
    }

    // Block-level reduce across the 4 waves via LDS, one partial per block.
    __shared__ float lds_c[WAVES * HH];   // 16 KB
    __shared__ float lds_l[WAVES];
#pragma unroll
    for (int k = 0; k < 4; ++k)
        *(float4*)(lds_c + wave * HH + k * 256 + lane * 4) = acc[k];
    if (lane == 0) lds_l[wave] = l;       // l is lane-replicated in a wave
    __syncthreads();

    float4 c = *(const float4*)(lds_c + tid * 4);
#pragma unroll
    for (int wv2 = 1; wv2 < WAVES; ++wv2) {
        float4 o = *(const float4*)(lds_c + wv2 * HH + tid * 4);
        c.x += o.x; c.y += o.y; c.z += o.z; c.w += o.w;
    }
    *(float4*)(pc + (long long)blk * HH + tid * 4) = c;
    if (tid == 0)
        pl[blk] = lds_l[0] + lds_l[1] + lds_l[2] + lds_l[3];
}

// Pass 2: combine CHUNKS partials per batch, normalize.
__global__ __launch_bounds__(256) void attn_pass2(
    const float* __restrict__ pc, const float* __restrict__ pl,
    float* __restrict__ out)
{
    const int b = blockIdx.x;
    const int t = threadIdx.x;
    float l = 0.f;
    float4 c = make_float4(0.f, 0.f, 0.f, 0.f);
#pragma unroll
    for (int i = 0; i < CHUNKS; ++i) {
        const int blk = b * CHUNKS + i;
        l += pl[blk];
        float4 o = *(const float4*)(pc + (long long)blk * HH + t * 4);
        c.x += o.x; c.y += o.y; c.z += o.z; c.w += o.w;
    }
    const float inv = 1.f / l;
    float4 r = make_float4(c.x * inv, c.y * inv, c.z * inv, c.w * inv);
    *(float4*)(out + (long long)b * HH + t * 4) = r;
}

extern "C" void kernel_launch(void* const* d_in, const int* in_sizes, int n_in,
                              void* d_out, int out_size, void* d_ws, size_t ws_size,
                              hipStream_t stream) {
    const float* x = (const float*)d_in[0];   // [B,S,H] fp32
    const float* w = (const float*)d_in[1];   // [H] fp32
    float* out = (float*)d_out;               // [B,H] fp32

    float* pc = (float*)d_ws;                           // [B*CHUNKS, H]
    float* pl = pc + (size_t)BB * CHUNKS * HH;          // [B*CHUNKS]

    attn_pass1<<<BB * CHUNKS, 256, 0, stream>>>(x, w, pc, pl);
    attn_pass2<<<BB, 256, 0, stream>>>(pc, pl, out);
}